// Round 4
// baseline (342.549 us; speedup 1.0000x reference)
//
#include <hip/hip_runtime.h>
#include <hip/hip_fp16.h>
#include <math.h>

// ---------------------------------------------------------------------------
// DevignLite: 3-layer GCN + mean/max pool + MLP head.  N=100000, E=1.6M,
// D=64, G=256.
// Round 20: resubmit of r18/r19 (GPUAcquisitionTimeout x2, never measured).
// Node-major feature rows ([Npad][64] fp16, row=128B) + aggregate
// restructure: 1 wave = 1 node, lane = feature.  Per edge: 1 coalesced
// u16 load (wave reads exactly the 128B row) + cvt + add; edge indices are
// wave-uniform -> csrc via scalar loads, row base via SALU.  Kills the
// 4x-per-slab edge revisit AND the 48-inst/wave shuffle reduction.
// k_mfmamm read/write and k_pool read updated to node-major (pool read is
// now one contiguous 128B line per node).
// Predicted: agg 48.4 -> ~30us each; FETCH_SIZE up (12.8MB gather set >
// 4MB/XCD L2) but L3-served; total 333 -> ~275us.
// Ledger: r12=372; r13 ticket fusion REVERTED; r14 pool fusion REVERTED;
// r15=366; r16 infra-fail; r17=333.5 (baseline, agg=3x48.4, VALU 57%,
// HBM 12.6%); r18 infra-fail; r19 infra-fail.
// ---------------------------------------------------------------------------

#define BKT_LOG 9
#define BKT (1 << BKT_LOG)
#define CHUNK 4096

typedef _Float16 h2 __attribute__((ext_vector_type(2)));
typedef _Float16 f16x8 __attribute__((ext_vector_type(8)));
typedef float f32x4 __attribute__((ext_vector_type(4)));

// W conversion to fp16 B-frag layout (blocks 0-2) + workspace zeroing
// (block 3: bucket cursors, block 4: hsum/hmax/cntg).  Launched first.
__global__ __launch_bounds__(256) void k_wcvt(const float* __restrict__ W0,
                                              const float* __restrict__ W1,
                                              const float* __restrict__ W2,
                                              _Float16* __restrict__ Wf,
                                              int* __restrict__ gcur,
                                              float* __restrict__ hz, int hzn) {
  if (blockIdx.x < 3) {
    const float* W = (blockIdx.x == 0) ? W0 : (blockIdx.x == 1) ? W1 : W2;
    _Float16* out = Wf + blockIdx.x * 4096;
    for (int i = threadIdx.x; i < 4096; i += 256) {
      int c = i >> 10, s = (i >> 9) & 1, l = (i >> 3) & 63, j = i & 7;
      int k = 32 * s + 8 * (l >> 4) + j;
      int ncol = 16 * c + (l & 15);
      out[i] = (_Float16)W[k * 64 + ncol];
    }
  } else if (blockIdx.x == 3) {
    gcur[threadIdx.x] = 0;
  } else {
    for (int i = threadIdx.x; i < hzn; i += 256) hz[i] = 0.f;
  }
}

// partition: scatter packed (local_dst<<17 | src) into per-bucket padded
// regions (bucket b owns ebuf[b*S .. b*S+S)).  Cursors zero-initialized;
// block claims a contiguous slice per bucket -> single writer per line.
// LDS-staged: src/dst read exactly once from HBM.
__global__ __launch_bounds__(256) void k_part(const int* __restrict__ src,
                                              const int* __restrict__ dst,
                                              int* __restrict__ gcur,
                                              int* __restrict__ ebuf,
                                              int E, int S) {
  __shared__ int sA[CHUNK];
  __shared__ int dA[CHUNK];
  __shared__ int h[256], base[256];
  int tid = threadIdx.x;
  long c0 = (long)blockIdx.x * CHUNK;
  int m = (int)min((long)CHUNK, (long)E - c0);
  h[tid] = 0;
  __syncthreads();
  for (int i = tid; i < m; i += 256) {
    int s = src[c0 + i];
    int d = dst[c0 + i];
    sA[i] = s;
    dA[i] = d;
    atomicAdd(&h[d >> BKT_LOG], 1);
  }
  __syncthreads();
  if (h[tid]) base[tid] = atomicAdd(&gcur[tid], h[tid]);
  __syncthreads();
  h[tid] = 0;   // reuse as per-bucket cursor
  __syncthreads();
  for (int i = tid; i < m; i += 256) {
    int s = sA[i], d = dA[i];
    int k = d >> BKT_LOG;
    int p = base[k] + atomicAdd(&h[k], 1);
    if (p < S)   // overflow guard (S = mean+45sigma: never taken in practice)
      ebuf[k * S + p] = ((d & (BKT - 1)) << 17) | s;
  }
}

// per-bucket: node histogram + scan in LDS -> off/end/dinv, then place csrc
// within the bucket's padded region (single-writer).
__global__ __launch_bounds__(512) void k_bplace(const int* __restrict__ ebuf,
                                                const int* __restrict__ gcur,
                                                int* __restrict__ off,
                                                int* __restrict__ eend,
                                                int* __restrict__ csrc,
                                                float* __restrict__ dinv,
                                                int N, int S) {
  __shared__ int s[512];
  __shared__ int cur[512];
  int b = blockIdx.x, tid = threadIdx.x;
  int n0 = b << BKT_LOG;
  int nn = min(BKT, N - n0);
  int e0 = b * S;
  int cnt = min(gcur[b], S);
  s[tid] = 0;
  __syncthreads();
  for (int e = tid; e < cnt; e += 512) atomicAdd(&s[ebuf[e0 + e] >> 17], 1);
  __syncthreads();
  int deg = s[tid];
  for (int d = 1; d < 512; d <<= 1) {
    int t = (tid >= d) ? s[tid - d] : 0;
    __syncthreads();
    s[tid] += t;
    __syncthreads();
  }
  int excl = s[tid] - deg;
  if (tid < nn) {
    off[n0 + tid] = e0 + excl;
    eend[n0 + tid] = e0 + excl + deg;
    dinv[n0 + tid] = 1.0f / sqrtf((float)(1 + deg));
  }
  cur[tid] = excl;
  __syncthreads();
  for (int e = tid; e < cnt; e += 512) {
    int p = ebuf[e0 + e];
    int pos = e0 + atomicAdd(&cur[p >> 17], 1);
    csrc[pos] = p & 0x1FFFF;
  }
}

// ---------------------------------------------------------------------------
// MFMA matmul: xh[node][64] = fp16( (in[node] @ W) * dinv[node]*scale )
// EMB: in = fp32 emb rows gathered by tok; else fp16 y in node-major layout.
// ---------------------------------------------------------------------------
template <bool EMB>
__global__ __launch_bounds__(256) void k_mfmamm(const _Float16* __restrict__ y,
                                                const int* __restrict__ tok,
                                                const float* __restrict__ emb,
                                                const _Float16* __restrict__ Wf,
                                                const float* __restrict__ dinv,
                                                float scale,
                                                _Float16* __restrict__ xh,
                                                int n) {
  __shared__ _Float16 lds[4 * 16 * 72];
  int w = threadIdx.x >> 6, l = threadIdx.x & 63;
  int m = l & 15, q = l >> 4;
  int rbase = blockIdx.x * 64 + w * 16;

  f16x8 a0, a1;
  if (EMB) {
    int node = min(rbase + m, n - 1);
    const float* er = emb + (size_t)tok[node] * 64;
    float4 v0 = *(const float4*)(er + q * 8);
    float4 v1 = *(const float4*)(er + q * 8 + 4);
    float4 v2 = *(const float4*)(er + 32 + q * 8);
    float4 v3 = *(const float4*)(er + 32 + q * 8 + 4);
    a0[0] = (_Float16)v0.x; a0[1] = (_Float16)v0.y; a0[2] = (_Float16)v0.z; a0[3] = (_Float16)v0.w;
    a0[4] = (_Float16)v1.x; a0[5] = (_Float16)v1.y; a0[6] = (_Float16)v1.z; a0[7] = (_Float16)v1.w;
    a1[0] = (_Float16)v2.x; a1[1] = (_Float16)v2.y; a1[2] = (_Float16)v2.z; a1[3] = (_Float16)v2.w;
    a1[4] = (_Float16)v3.x; a1[5] = (_Float16)v3.y; a1[6] = (_Float16)v3.z; a1[7] = (_Float16)v3.w;
  } else {
    int node = rbase + m;
    const _Float16* yr = y + ((size_t)(unsigned)node << 6);
    a0 = *(const f16x8*)(yr + q * 8);
    a1 = *(const f16x8*)(yr + 32 + q * 8);
  }
  float4 d4 = *(const float4*)(dinv + rbase + q * 4);

  const f16x8* wf = (const f16x8*)Wf + l;
  f32x4 acc[4];
#pragma unroll
  for (int c = 0; c < 4; c++) {
    f32x4 z = {0.f, 0.f, 0.f, 0.f};
    z = __builtin_amdgcn_mfma_f32_16x16x32_f16(a0, wf[(c * 2 + 0) * 64], z, 0, 0, 0);
    z = __builtin_amdgcn_mfma_f32_16x16x32_f16(a1, wf[(c * 2 + 1) * 64], z, 0, 0, 0);
    acc[c] = z;
  }

  const float ds[4] = {d4.x * scale, d4.y * scale, d4.z * scale, d4.w * scale};
  _Float16* ldw = lds + w * 16 * 72;
#pragma unroll
  for (int c = 0; c < 4; c++)
#pragma unroll
    for (int r = 0; r < 4; r++)
      ldw[(q * 4 + r) * 72 + c * 16 + m] = (_Float16)(acc[c][r] * ds[r]);
  __syncthreads();

  int row2 = l & 15, c2 = l >> 4;
  int node = rbase + row2;
  if (node < n) {
    const uint4* s4 = (const uint4*)(ldw + row2 * 72 + c2 * 16);
    uint4 v0 = s4[0], v1 = s4[1];
    uint4* dst = (uint4*)(xh + ((size_t)(unsigned)node << 6) + c2 * 16);
    dst[0] = v0;
    dst[1] = v1;
  }
}

// ---------------------------------------------------------------------------
// Aggregate: 1 wave = 1 node, lane = feature.  Node-major rows (128B):
// per edge one coalesced u16 load (wave reads the full row) + cvt + add.
// Edge list is wave-uniform -> csrc via scalar loads, row base via SALU.
// out[t][64] = fp16 4096*relu((xh[t] + sum_in xh[s]) * dinv[t]/256 + bias).
// ---------------------------------------------------------------------------
__global__ __launch_bounds__(256) void k_aggregate(const int* __restrict__ off,
                                                   const int* __restrict__ eend,
                                                   const int* __restrict__ csrc,
                                                   const float* __restrict__ dinv,
                                                   const _Float16* __restrict__ xh,
                                                   const float* __restrict__ bias,
                                                   _Float16* __restrict__ outp,
                                                   int n) {
  int lane = threadIdx.x & 63;
  int t = __builtin_amdgcn_readfirstlane(blockIdx.x * 4 + (threadIdx.x >> 6));
  if (t >= n) return;
  int e0 = off[t];
  int e1 = eend[t];

  float acc = (float)xh[((size_t)(unsigned)t << 6) + lane];   // self term
  int e = e0;
  for (; e + 4 <= e1; e += 4) {
    int s0 = csrc[e];
    int s1 = csrc[e + 1];
    int s2 = csrc[e + 2];
    int s3 = csrc[e + 3];
    float v0 = (float)xh[((size_t)(unsigned)s0 << 6) + lane];
    float v1 = (float)xh[((size_t)(unsigned)s1 << 6) + lane];
    float v2 = (float)xh[((size_t)(unsigned)s2 << 6) + lane];
    float v3 = (float)xh[((size_t)(unsigned)s3 << 6) + lane];
    acc += v0;
    acc += v1;
    acc += v2;
    acc += v3;
  }
  for (; e < e1; ++e)
    acc += (float)xh[((size_t)(unsigned)csrc[e] << 6) + lane];

  float sc = dinv[t] * (1.0f / 256.0f);
  float o = fmaxf(acc * sc + bias[lane], 0.f) * 4096.f;
  outp[((size_t)(unsigned)t << 6) + lane] = (_Float16)o;
}

// batch is sorted: per-wave register segment reduction over node-major fp16 y.
// lane = feature; per node one contiguous 128B row read.
__global__ __launch_bounds__(256) void k_pool(const _Float16* __restrict__ x,
                                              const int* __restrict__ batch,
                                              float* __restrict__ hsum,
                                              float* __restrict__ hmax,
                                              int* __restrict__ cntg,
                                              int n) {
  int wid = (blockIdx.x * blockDim.x + threadIdx.x) >> 6;
  int lane = threadIdx.x & 63;
  int i0 = wid * 64;
  if (i0 >= n) return;
  int i1 = min(i0 + 64, n);
  int batch_l = (i0 + lane < n) ? batch[i0 + lane] : 0;
  float gsum = 0.f, gmax = 0.f;
  int cur = __shfl(batch_l, 0);
  int c = 0;
  for (int i = i0; i < i1; i++) {
    int g = __shfl(batch_l, i - i0);
    if (g != cur) {
      atomicAdd(&hsum[cur * 64 + lane], gsum);
      atomicMax((int*)&hmax[cur * 64 + lane], __float_as_int(gmax));
      if (lane == 0) atomicAdd(&cntg[cur], c);
      gsum = 0.f; gmax = 0.f; c = 0; cur = g;
    }
    float v = (float)x[((size_t)(unsigned)i << 6) + lane];   // relu+bias folded, x4096
    gsum += v;
    gmax = fmaxf(gmax, v);
    c++;
  }
  atomicAdd(&hsum[cur * 64 + lane], gsum);
  atomicMax((int*)&hmax[cur * 64 + lane], __float_as_int(gmax));
  if (lane == 0) atomicAdd(&cntg[cur], c);
}

// one block (64 threads) per graph: logits = relu(h@Wc1+bc1)@Wc2+bc2
// hsum/hmax carry the 4096x scale; undone here.
__global__ __launch_bounds__(64) void k_cls(const float* __restrict__ hsum,
                                            const float* __restrict__ hmax,
                                            const int* __restrict__ cnt,
                                            const float* __restrict__ Wc1,
                                            const float* __restrict__ bc1,
                                            const float* __restrict__ Wc2,
                                            const float* __restrict__ bc2,
                                            float* __restrict__ out) {
  __shared__ float h[128];
  __shared__ float hid[64];
  int g = blockIdx.x, j = threadIdx.x;
  int c = cnt[g];
  float cf = (float)(c > 0 ? c : 1);
  h[j] = hsum[g * 64 + j] / cf * (1.0f / 4096.0f);
  h[64 + j] = hmax[g * 64 + j] * (1.0f / 4096.0f);
  __syncthreads();
  float acc = bc1[j];
  for (int k = 0; k < 128; k++) acc += h[k] * Wc1[k * 64 + j];
  hid[j] = fmaxf(acc, 0.f);
  __syncthreads();
  if (j < 2) {
    float a = bc2[j];
    for (int k = 0; k < 64; k++) a += hid[k] * Wc2[k * 2 + j];
    out[g * 2 + j] = a;
  }
}

extern "C" void kernel_launch(void* const* d_in, const int* in_sizes, int n_in,
                              void* d_out, int out_size, void* d_ws, size_t ws_size,
                              hipStream_t stream) {
  const int N = in_sizes[0];
  const int E = in_sizes[1] / 2;
  const int G = out_size / 2;
  const int B = (N + BKT - 1) >> BKT_LOG;
  const int Npad = (N + 63) & ~63;
  // padded bucket stride: 1.5x mean occupancy + 256, rounded to 4
  const int S = ((((E + B - 1) / B) * 3 / 2 + 256) + 3) & ~3;

  const int* tok   = (const int*)d_in[0];
  const int* ei    = (const int*)d_in[1];
  const int* batch = (const int*)d_in[2];
  const float* emb = (const float*)d_in[3];
  const float* W0 = (const float*)d_in[4];  const float* b0 = (const float*)d_in[5];
  const float* W1 = (const float*)d_in[6];  const float* b1 = (const float*)d_in[7];
  const float* W2 = (const float*)d_in[8];  const float* b2 = (const float*)d_in[9];
  const float* Wc1 = (const float*)d_in[10]; const float* bc1 = (const float*)d_in[11];
  const float* Wc2 = (const float*)d_in[12]; const float* bc2 = (const float*)d_in[13];
  const int* srcp = ei;
  const int* dstp = ei + E;

  // ---- workspace carve-up (4-byte units) ----
  int* off    = (int*)d_ws;                      // N
  int* eend   = off + N;                         // N
  float* dinv = (float*)(eend + N);              // Npad
  int* gcur   = (int*)(dinv + Npad);             // 256
  _Float16* Wf = (_Float16*)(gcur + 256);        // 3*4096 halfs (24 KB)
  int* csrc   = (int*)(Wf + 3 * 4096);           // B*S (padded, ~9.6 MB)
  _Float16* xh = (_Float16*)(csrc + (size_t)B * S);  // Npad x 64 (node-major)
  _Float16* y  = xh + (size_t)Npad * 64;         // Npad x 64 (node-major)
  int* ebuf   = (int*)y;                         // B*S ints, aliases y (dead
                                                 // before first aggregate)
  float* hsum = (float*)(y + (size_t)Npad * 64); // G*64
  float* hmax = hsum + (size_t)G * 64;           // G*64
  int*   cntg = (int*)(hmax + (size_t)G * 64);   // G

  auto cdiv = [](long a, long b) { return (int)((a + b - 1) / b); };
  const int aggBlocks = cdiv(N, 4);   // 1 wave = 1 node, 4 waves/block

  // ---- weight conversion + workspace zeroing ----
  k_wcvt<<<5, 256, 0, stream>>>(W0, W1, W2, Wf, gcur, hsum, G * 129);

  // ---- CSR build (padded buckets; no histogram/scan kernels) ----
  k_part<<<cdiv(E, CHUNK), 256, 0, stream>>>(srcp, dstp, gcur, ebuf, E, S);
  k_bplace<<<B, 512, 0, stream>>>(ebuf, gcur, off, eend, csrc, dinv, N, S);

  // ---- 3 GCN layers ----
  k_mfmamm<true><<<cdiv(N, 64), 256, 0, stream>>>(nullptr, tok, emb, Wf, dinv, 256.f, xh, N);
  k_aggregate<<<aggBlocks, 256, 0, stream>>>(off, eend, csrc, dinv, xh, b0, y, N);

  k_mfmamm<false><<<cdiv(N, 64), 256, 0, stream>>>(y, nullptr, nullptr, Wf + 4096, dinv, 1.f / 16.f, xh, N);
  k_aggregate<<<aggBlocks, 256, 0, stream>>>(off, eend, csrc, dinv, xh, b1, y, N);

  k_mfmamm<false><<<cdiv(N, 64), 256, 0, stream>>>(y, nullptr, nullptr, Wf + 8192, dinv, 1.f / 16.f, xh, N);
  k_aggregate<<<aggBlocks, 256, 0, stream>>>(off, eend, csrc, dinv, xh, b2, y, N);

  // ---- pooling ----
  k_pool<<<cdiv(N, 256), 256, 0, stream>>>(y, batch, hsum, hmax, cntg, N);

  // ---- classifier head ----
  k_cls<<<G, 64, 0, stream>>>(hsum, hmax, cntg, Wc1, bc1, Wc2, bc2, (float*)d_out);
}

// Round 5
// 332.280 us; speedup vs baseline: 1.0309x; 1.0309x over previous
//
#include <hip/hip_runtime.h>
#include <hip/hip_fp16.h>
#include <math.h>

// ---------------------------------------------------------------------------
// DevignLite: 3-layer GCN + mean/max pool + MLP head.  N=100000, E=1.6M,
// D=64, G=256.
// Round 21: deep-MLP aggregate.  r20 post-mortem: node-major halved VALU
// (57->20%) and tripled FETCH (35->91MB) yet dur identical (48.4 vs 48.9us)
// -> not instruction-bound, not cache-bound; hypothesis: ~4 serial memory
// rounds/wave dominate (T-lat) vs a ~4.2TB/s gather ceiling (T-bw).
// This round discriminates: lane=(p:2b edge-slot, f:4b feat-quad); per
// macro-round each group loads 8 consecutive edge ids (2 aligned int4) and
// 8 rows dwordx2 -> 32 edges in flight; mean node = ONE exposed round.
// Self-loop folded into CSR (k_bplace seeds csrc with t; deg includes self)
// so the aggregate loop is uniform.  S rounded to 8 for int4 alignment;
// windows start at e0&~7 with per-edge predicates (padded region => safe).
// Predicted: T-lat -> agg ~12-20us, total ~230-260; T-bw -> agg ~49
// unchanged -> pivot to byte reduction next.
// Ledger: r12=372; r15=366; r17=333.5 (agg 3x48.4, VALU57%, FETCH 35MB);
// r20=342.5 (node-major: agg 3x48.9, VALU20%, FETCH 91MB) -> dur invariant.
// ---------------------------------------------------------------------------

#define BKT_LOG 9
#define BKT (1 << BKT_LOG)
#define CHUNK 4096

typedef _Float16 h2 __attribute__((ext_vector_type(2)));
typedef _Float16 f16x4 __attribute__((ext_vector_type(4)));
typedef _Float16 f16x8 __attribute__((ext_vector_type(8)));
typedef float f32x4 __attribute__((ext_vector_type(4)));

union HU { unsigned u; h2 h; };
__device__ inline h2 h2bits(unsigned u) { HU x; x.u = u; return x.h; }

#if __has_builtin(__builtin_amdgcn_fdot2)
#define FDOT2(a, b, c) __builtin_amdgcn_fdot2((a), (b), (c), false)
#else
__device__ inline float FDOT2(h2 a, h2 b, float c) {
  return (float)a.x * (float)b.x + (float)a.y * (float)b.y + c;
}
#endif

#define MASK_X 0x00003C00u   // half2 (1,0)
#define MASK_Y 0x3C000000u   // half2 (0,1)

// acc 4 floats += the 4 halfs packed in v (via fdot2 unit masks)
__device__ inline void acc4c(uint2 v, float& a0, float& a1, float& a2, float& a3) {
  h2 lo = h2bits(v.x), hi = h2bits(v.y);
  a0 = FDOT2(lo, h2bits(MASK_X), a0);
  a1 = FDOT2(lo, h2bits(MASK_Y), a1);
  a2 = FDOT2(hi, h2bits(MASK_X), a2);
  a3 = FDOT2(hi, h2bits(MASK_Y), a3);
}

// W conversion to fp16 B-frag layout (blocks 0-2) + workspace zeroing
// (block 3: bucket cursors, block 4: hsum/hmax/cntg).  Launched first.
__global__ __launch_bounds__(256) void k_wcvt(const float* __restrict__ W0,
                                              const float* __restrict__ W1,
                                              const float* __restrict__ W2,
                                              _Float16* __restrict__ Wf,
                                              int* __restrict__ gcur,
                                              float* __restrict__ hz, int hzn) {
  if (blockIdx.x < 3) {
    const float* W = (blockIdx.x == 0) ? W0 : (blockIdx.x == 1) ? W1 : W2;
    _Float16* out = Wf + blockIdx.x * 4096;
    for (int i = threadIdx.x; i < 4096; i += 256) {
      int c = i >> 10, s = (i >> 9) & 1, l = (i >> 3) & 63, j = i & 7;
      int k = 32 * s + 8 * (l >> 4) + j;
      int ncol = 16 * c + (l & 15);
      out[i] = (_Float16)W[k * 64 + ncol];
    }
  } else if (blockIdx.x == 3) {
    gcur[threadIdx.x] = 0;
  } else {
    for (int i = threadIdx.x; i < hzn; i += 256) hz[i] = 0.f;
  }
}

// partition: scatter packed (local_dst<<17 | src) into per-bucket padded
// regions (bucket b owns ebuf[b*S .. b*S+S)).  Cursors zero-initialized;
// block claims a contiguous slice per bucket -> single writer per line.
// LDS-staged: src/dst read exactly once from HBM.
__global__ __launch_bounds__(256) void k_part(const int* __restrict__ src,
                                              const int* __restrict__ dst,
                                              int* __restrict__ gcur,
                                              int* __restrict__ ebuf,
                                              int E, int S) {
  __shared__ int sA[CHUNK];
  __shared__ int dA[CHUNK];
  __shared__ int h[256], base[256];
  int tid = threadIdx.x;
  long c0 = (long)blockIdx.x * CHUNK;
  int m = (int)min((long)CHUNK, (long)E - c0);
  h[tid] = 0;
  __syncthreads();
  for (int i = tid; i < m; i += 256) {
    int s = src[c0 + i];
    int d = dst[c0 + i];
    sA[i] = s;
    dA[i] = d;
    atomicAdd(&h[d >> BKT_LOG], 1);
  }
  __syncthreads();
  if (h[tid]) base[tid] = atomicAdd(&gcur[tid], h[tid]);
  __syncthreads();
  h[tid] = 0;   // reuse as per-bucket cursor
  __syncthreads();
  for (int i = tid; i < m; i += 256) {
    int s = sA[i], d = dA[i];
    int k = d >> BKT_LOG;
    int p = base[k] + atomicAdd(&h[k], 1);
    if (p < S)   // overflow guard (S = mean+45sigma: never taken in practice)
      ebuf[k * S + p] = ((d & (BKT - 1)) << 17) | s;
  }
}

// per-bucket: node histogram (seeded with self-loop) + scan in LDS ->
// off/end/dinv, then place csrc (self first, then in-edges) within the
// bucket's padded region (single-writer).  deg includes self.
__global__ __launch_bounds__(512) void k_bplace(const int* __restrict__ ebuf,
                                                const int* __restrict__ gcur,
                                                int* __restrict__ off,
                                                int* __restrict__ eend,
                                                int* __restrict__ csrc,
                                                float* __restrict__ dinv,
                                                int N, int S) {
  __shared__ int s[512];
  __shared__ int cur[512];
  int b = blockIdx.x, tid = threadIdx.x;
  int n0 = b << BKT_LOG;
  int nn = min(BKT, N - n0);
  int e0 = b * S;
  int cnt = min(gcur[b], S - nn);   // reserve room for self-loops
  s[tid] = (tid < nn) ? 1 : 0;      // self-loop seed
  __syncthreads();
  for (int e = tid; e < cnt; e += 512) atomicAdd(&s[ebuf[e0 + e] >> 17], 1);
  __syncthreads();
  int degws = s[tid];               // 1 + in-degree (0 for phantom slots)
  for (int d = 1; d < 512; d <<= 1) {
    int t = (tid >= d) ? s[tid - d] : 0;
    __syncthreads();
    s[tid] += t;
    __syncthreads();
  }
  int excl = s[tid] - degws;
  if (tid < nn) {
    off[n0 + tid] = e0 + excl;
    eend[n0 + tid] = e0 + excl + degws;
    dinv[n0 + tid] = 1.0f / sqrtf((float)degws);
    csrc[e0 + excl] = n0 + tid;     // self first
  }
  cur[tid] = excl + ((tid < nn) ? 1 : 0);
  __syncthreads();
  for (int e = tid; e < cnt; e += 512) {
    int p = ebuf[e0 + e];
    int pos = e0 + atomicAdd(&cur[p >> 17], 1);
    csrc[pos] = p & 0x1FFFF;
  }
}

// ---------------------------------------------------------------------------
// MFMA matmul: xh[node][64] = fp16( (in[node] @ W) * dinv[node]*scale )
// EMB: in = fp32 emb rows gathered by tok; else fp16 y in node-major layout.
// ---------------------------------------------------------------------------
template <bool EMB>
__global__ __launch_bounds__(256) void k_mfmamm(const _Float16* __restrict__ y,
                                                const int* __restrict__ tok,
                                                const float* __restrict__ emb,
                                                const _Float16* __restrict__ Wf,
                                                const float* __restrict__ dinv,
                                                float scale,
                                                _Float16* __restrict__ xh,
                                                int n) {
  __shared__ _Float16 lds[4 * 16 * 72];
  int w = threadIdx.x >> 6, l = threadIdx.x & 63;
  int m = l & 15, q = l >> 4;
  int rbase = blockIdx.x * 64 + w * 16;

  f16x8 a0, a1;
  if (EMB) {
    int node = min(rbase + m, n - 1);
    const float* er = emb + (size_t)tok[node] * 64;
    float4 v0 = *(const float4*)(er + q * 8);
    float4 v1 = *(const float4*)(er + q * 8 + 4);
    float4 v2 = *(const float4*)(er + 32 + q * 8);
    float4 v3 = *(const float4*)(er + 32 + q * 8 + 4);
    a0[0] = (_Float16)v0.x; a0[1] = (_Float16)v0.y; a0[2] = (_Float16)v0.z; a0[3] = (_Float16)v0.w;
    a0[4] = (_Float16)v1.x; a0[5] = (_Float16)v1.y; a0[6] = (_Float16)v1.z; a0[7] = (_Float16)v1.w;
    a1[0] = (_Float16)v2.x; a1[1] = (_Float16)v2.y; a1[2] = (_Float16)v2.z; a1[3] = (_Float16)v2.w;
    a1[4] = (_Float16)v3.x; a1[5] = (_Float16)v3.y; a1[6] = (_Float16)v3.z; a1[7] = (_Float16)v3.w;
  } else {
    int node = rbase + m;
    const _Float16* yr = y + ((size_t)(unsigned)node << 6);
    a0 = *(const f16x8*)(yr + q * 8);
    a1 = *(const f16x8*)(yr + 32 + q * 8);
  }
  float4 d4 = *(const float4*)(dinv + rbase + q * 4);

  const f16x8* wf = (const f16x8*)Wf + l;
  f32x4 acc[4];
#pragma unroll
  for (int c = 0; c < 4; c++) {
    f32x4 z = {0.f, 0.f, 0.f, 0.f};
    z = __builtin_amdgcn_mfma_f32_16x16x32_f16(a0, wf[(c * 2 + 0) * 64], z, 0, 0, 0);
    z = __builtin_amdgcn_mfma_f32_16x16x32_f16(a1, wf[(c * 2 + 1) * 64], z, 0, 0, 0);
    acc[c] = z;
  }

  const float ds[4] = {d4.x * scale, d4.y * scale, d4.z * scale, d4.w * scale};
  _Float16* ldw = lds + w * 16 * 72;
#pragma unroll
  for (int c = 0; c < 4; c++)
#pragma unroll
    for (int r = 0; r < 4; r++)
      ldw[(q * 4 + r) * 72 + c * 16 + m] = (_Float16)(acc[c][r] * ds[r]);
  __syncthreads();

  int row2 = l & 15, c2 = l >> 4;
  int node = rbase + row2;
  if (node < n) {
    const uint4* s4 = (const uint4*)(ldw + row2 * 72 + c2 * 16);
    uint4 v0 = s4[0], v1 = s4[1];
    uint4* dst = (uint4*)(xh + ((size_t)(unsigned)node << 6) + c2 * 16);
    dst[0] = v0;
    dst[1] = v1;
  }
}

// ---------------------------------------------------------------------------
// Aggregate v3: 1 wave = 1 node; lane = (p:2b edge-slot, f:4b feature-quad).
// Per macro-round each 16-lane group owns 8 consecutive edges: 2 aligned
// int4 index loads + 8 dwordx2 row loads -> 32 edges in flight -> mean node
// completes in ONE exposed memory round.  Self-loop lives in csrc.
// out[t][64] = fp16 4096*relu(sum * dinv[t]/256 + bias).
// ---------------------------------------------------------------------------
__global__ __launch_bounds__(256) void k_aggregate(const int* __restrict__ off,
                                                   const int* __restrict__ eend,
                                                   const int* __restrict__ csrc,
                                                   const float* __restrict__ dinv,
                                                   const _Float16* __restrict__ xh,
                                                   const float* __restrict__ bias,
                                                   _Float16* __restrict__ outp,
                                                   int n) {
  int lane = threadIdx.x & 63;
  int t = blockIdx.x * 4 + (threadIdx.x >> 6);
  if (t >= n) return;
  int e0 = off[t];
  int e1 = eend[t];
  int p = lane >> 4;        // edge-slot group
  int f = lane & 15;        // feature quad (features 4f..4f+3)
  const char* xb = (const char*)xh;

  float a0 = 0.f, a1 = 0.f, a2 = 0.f, a3 = 0.f;
  for (int base = (e0 & ~7); base < e1; base += 32) {
    int my = base + p * 8;
    int4 iA = {0, 0, 0, 0}, iB = {0, 0, 0, 0};
    if (my < e1) iA = *(const int4*)(csrc + my);          // 32B-aligned
    if (my + 4 < e1) iB = *(const int4*)(csrc + my + 4);  // 16B-aligned
    uint2 v0 = {0,0}, v1 = {0,0}, v2 = {0,0}, v3 = {0,0};
    uint2 v4 = {0,0}, v5 = {0,0}, v6 = {0,0}, v7 = {0,0};
    if (my + 0 >= e0 && my + 0 < e1) v0 = *(const uint2*)(xb + ((size_t)(unsigned)iA.x << 7) + f * 8);
    if (my + 1 >= e0 && my + 1 < e1) v1 = *(const uint2*)(xb + ((size_t)(unsigned)iA.y << 7) + f * 8);
    if (my + 2 >= e0 && my + 2 < e1) v2 = *(const uint2*)(xb + ((size_t)(unsigned)iA.z << 7) + f * 8);
    if (my + 3 >= e0 && my + 3 < e1) v3 = *(const uint2*)(xb + ((size_t)(unsigned)iA.w << 7) + f * 8);
    if (my + 4 >= e0 && my + 4 < e1) v4 = *(const uint2*)(xb + ((size_t)(unsigned)iB.x << 7) + f * 8);
    if (my + 5 >= e0 && my + 5 < e1) v5 = *(const uint2*)(xb + ((size_t)(unsigned)iB.y << 7) + f * 8);
    if (my + 6 >= e0 && my + 6 < e1) v6 = *(const uint2*)(xb + ((size_t)(unsigned)iB.z << 7) + f * 8);
    if (my + 7 >= e0 && my + 7 < e1) v7 = *(const uint2*)(xb + ((size_t)(unsigned)iB.w << 7) + f * 8);
    acc4c(v0, a0, a1, a2, a3);
    acc4c(v1, a0, a1, a2, a3);
    acc4c(v2, a0, a1, a2, a3);
    acc4c(v3, a0, a1, a2, a3);
    acc4c(v4, a0, a1, a2, a3);
    acc4c(v5, a0, a1, a2, a3);
    acc4c(v6, a0, a1, a2, a3);
    acc4c(v7, a0, a1, a2, a3);
  }

  // reduce across the 4 p-groups (lane bits 4-5)
  a0 += __shfl_xor(a0, 16); a0 += __shfl_xor(a0, 32);
  a1 += __shfl_xor(a1, 16); a1 += __shfl_xor(a1, 32);
  a2 += __shfl_xor(a2, 16); a2 += __shfl_xor(a2, 32);
  a3 += __shfl_xor(a3, 16); a3 += __shfl_xor(a3, 32);

  if (p == 0) {
    float sc = dinv[t] * (1.0f / 256.0f);
    float4 bb = *(const float4*)(bias + f * 4);
    f16x4 hv;
    hv[0] = (_Float16)(fmaxf(a0 * sc + bb.x, 0.f) * 4096.f);
    hv[1] = (_Float16)(fmaxf(a1 * sc + bb.y, 0.f) * 4096.f);
    hv[2] = (_Float16)(fmaxf(a2 * sc + bb.z, 0.f) * 4096.f);
    hv[3] = (_Float16)(fmaxf(a3 * sc + bb.w, 0.f) * 4096.f);
    *(f16x4*)((char*)outp + ((size_t)(unsigned)t << 7) + f * 8) = hv;
  }
}

// batch is sorted: per-wave register segment reduction over node-major fp16 y.
// lane = feature; per node one contiguous 128B row read.
__global__ __launch_bounds__(256) void k_pool(const _Float16* __restrict__ x,
                                              const int* __restrict__ batch,
                                              float* __restrict__ hsum,
                                              float* __restrict__ hmax,
                                              int* __restrict__ cntg,
                                              int n) {
  int wid = (blockIdx.x * blockDim.x + threadIdx.x) >> 6;
  int lane = threadIdx.x & 63;
  int i0 = wid * 64;
  if (i0 >= n) return;
  int i1 = min(i0 + 64, n);
  int batch_l = (i0 + lane < n) ? batch[i0 + lane] : 0;
  float gsum = 0.f, gmax = 0.f;
  int cur = __shfl(batch_l, 0);
  int c = 0;
  for (int i = i0; i < i1; i++) {
    int g = __shfl(batch_l, i - i0);
    if (g != cur) {
      atomicAdd(&hsum[cur * 64 + lane], gsum);
      atomicMax((int*)&hmax[cur * 64 + lane], __float_as_int(gmax));
      if (lane == 0) atomicAdd(&cntg[cur], c);
      gsum = 0.f; gmax = 0.f; c = 0; cur = g;
    }
    float v = (float)x[((size_t)(unsigned)i << 6) + lane];   // relu+bias folded, x4096
    gsum += v;
    gmax = fmaxf(gmax, v);
    c++;
  }
  atomicAdd(&hsum[cur * 64 + lane], gsum);
  atomicMax((int*)&hmax[cur * 64 + lane], __float_as_int(gmax));
  if (lane == 0) atomicAdd(&cntg[cur], c);
}

// one block (64 threads) per graph: logits = relu(h@Wc1+bc1)@Wc2+bc2
// hsum/hmax carry the 4096x scale; undone here.
__global__ __launch_bounds__(64) void k_cls(const float* __restrict__ hsum,
                                            const float* __restrict__ hmax,
                                            const int* __restrict__ cnt,
                                            const float* __restrict__ Wc1,
                                            const float* __restrict__ bc1,
                                            const float* __restrict__ Wc2,
                                            const float* __restrict__ bc2,
                                            float* __restrict__ out) {
  __shared__ float h[128];
  __shared__ float hid[64];
  int g = blockIdx.x, j = threadIdx.x;
  int c = cnt[g];
  float cf = (float)(c > 0 ? c : 1);
  h[j] = hsum[g * 64 + j] / cf * (1.0f / 4096.0f);
  h[64 + j] = hmax[g * 64 + j] * (1.0f / 4096.0f);
  __syncthreads();
  float acc = bc1[j];
  for (int k = 0; k < 128; k++) acc += h[k] * Wc1[k * 64 + j];
  hid[j] = fmaxf(acc, 0.f);
  __syncthreads();
  if (j < 2) {
    float a = bc2[j];
    for (int k = 0; k < 64; k++) a += hid[k] * Wc2[k * 2 + j];
    out[g * 2 + j] = a;
  }
}

extern "C" void kernel_launch(void* const* d_in, const int* in_sizes, int n_in,
                              void* d_out, int out_size, void* d_ws, size_t ws_size,
                              hipStream_t stream) {
  const int N = in_sizes[0];
  const int E = in_sizes[1] / 2;
  const int G = out_size / 2;
  const int B = (N + BKT - 1) >> BKT_LOG;
  const int Npad = (N + 63) & ~63;
  // padded bucket stride: 1.5x mean occupancy + 256, rounded to 8 so that
  // bucket bases stay 8-int aligned (int4 index loads in k_aggregate)
  const int S = ((((E + B - 1) / B) * 3 / 2 + 256) + 7) & ~7;

  const int* tok   = (const int*)d_in[0];
  const int* ei    = (const int*)d_in[1];
  const int* batch = (const int*)d_in[2];
  const float* emb = (const float*)d_in[3];
  const float* W0 = (const float*)d_in[4];  const float* b0 = (const float*)d_in[5];
  const float* W1 = (const float*)d_in[6];  const float* b1 = (const float*)d_in[7];
  const float* W2 = (const float*)d_in[8];  const float* b2 = (const float*)d_in[9];
  const float* Wc1 = (const float*)d_in[10]; const float* bc1 = (const float*)d_in[11];
  const float* Wc2 = (const float*)d_in[12]; const float* bc2 = (const float*)d_in[13];
  const int* srcp = ei;
  const int* dstp = ei + E;

  // ---- workspace carve-up (4-byte units) ----
  int* off    = (int*)d_ws;                      // N
  int* eend   = off + N;                         // N
  float* dinv = (float*)(eend + N);              // Npad
  int* gcur   = (int*)(dinv + Npad);             // 256
  _Float16* Wf = (_Float16*)(gcur + 256);        // 3*4096 halfs (24 KB)
  int* csrc   = (int*)(Wf + 3 * 4096);           // B*S (padded, ~9.8 MB)
  _Float16* xh = (_Float16*)(csrc + (size_t)B * S);  // Npad x 64 (node-major)
  _Float16* y  = xh + (size_t)Npad * 64;         // Npad x 64 (node-major)
  int* ebuf   = (int*)y;                         // B*S ints, aliases y (dead
                                                 // before first aggregate)
  float* hsum = (float*)(y + (size_t)Npad * 64); // G*64
  float* hmax = hsum + (size_t)G * 64;           // G*64
  int*   cntg = (int*)(hmax + (size_t)G * 64);   // G

  auto cdiv = [](long a, long b) { return (int)((a + b - 1) / b); };
  const int aggBlocks = cdiv(N, 4);   // 1 wave = 1 node, 4 waves/block

  // ---- weight conversion + workspace zeroing ----
  k_wcvt<<<5, 256, 0, stream>>>(W0, W1, W2, Wf, gcur, hsum, G * 129);

  // ---- CSR build (padded buckets; self-loops folded in) ----
  k_part<<<cdiv(E, CHUNK), 256, 0, stream>>>(srcp, dstp, gcur, ebuf, E, S);
  k_bplace<<<B, 512, 0, stream>>>(ebuf, gcur, off, eend, csrc, dinv, N, S);

  // ---- 3 GCN layers ----
  k_mfmamm<true><<<cdiv(N, 64), 256, 0, stream>>>(nullptr, tok, emb, Wf, dinv, 256.f, xh, N);
  k_aggregate<<<aggBlocks, 256, 0, stream>>>(off, eend, csrc, dinv, xh, b0, y, N);

  k_mfmamm<false><<<cdiv(N, 64), 256, 0, stream>>>(y, nullptr, nullptr, Wf + 4096, dinv, 1.f / 16.f, xh, N);
  k_aggregate<<<aggBlocks, 256, 0, stream>>>(off, eend, csrc, dinv, xh, b1, y, N);

  k_mfmamm<false><<<cdiv(N, 64), 256, 0, stream>>>(y, nullptr, nullptr, Wf + 8192, dinv, 1.f / 16.f, xh, N);
  k_aggregate<<<aggBlocks, 256, 0, stream>>>(off, eend, csrc, dinv, xh, b2, y, N);

  // ---- pooling ----
  k_pool<<<cdiv(N, 256), 256, 0, stream>>>(y, batch, hsum, hmax, cntg, N);

  // ---- classifier head ----
  k_cls<<<G, 64, 0, stream>>>(hsum, hmax, cntg, Wc1, bc1, Wc2, bc2, (float*)d_out);
}